// Round 6
// baseline (1236.022 us; speedup 1.0000x reference)
//
#include <hip/hip_runtime.h>
#include <hip/hip_bf16.h>
#include <math.h>

#define NF 128          // feature width (both layers): 2 heads x 64

typedef __attribute__((ext_vector_type(8))) short short8v;   // 8 bf16
typedef __attribute__((ext_vector_type(4))) float float4v;   // MFMA acc

__device__ inline float leaky02(float v) { return v >= 0.0f ? v : 0.2f * v; }

// fp32 -> bf16 round-to-nearest-even
__device__ inline unsigned short f2bf(float x) {
    unsigned u = __float_as_uint(x);
    u = u + 0x7fffu + ((u >> 16) & 1u);
    return (unsigned short)(u >> 16);
}
__device__ inline float bf2f(unsigned short h) {
    return __uint_as_float(((unsigned)h) << 16);
}

// ---------------------------------------------------------------------------
// prep: (a) transposed bf16 hi/lo W panels WT[m][col][k]; (b) attention
// projections P[m][f][c] = sum_d W[m][f][h][d]*a[h][d], c={el0,el1,er0,er1};
// (c) per-layer bias sums bs[layer][c] = sum_r b[r][c].  m = layer*3+r.
// ---------------------------------------------------------------------------
__global__ __launch_bounds__(256) void prep(
    const float* __restrict__ W1, const float* __restrict__ W2,
    const float* __restrict__ al1, const float* __restrict__ ar1,
    const float* __restrict__ b1,
    const float* __restrict__ al2, const float* __restrict__ ar2,
    const float* __restrict__ b2,
    unsigned short* __restrict__ WThi, unsigned short* __restrict__ WTlo,
    float* __restrict__ P, float* __restrict__ bs)
{
    int i = blockIdx.x * 256 + threadIdx.x;
    if (i < 6 * 16384) {
        int m = i >> 14, rem = i & 16383, k = rem >> 7, col = rem & 127;
        const float* Wm = (m < 3) ? W1 + (size_t)m * 16384
                                  : W2 + (size_t)(m - 3) * 16384;
        float v = Wm[k * 128 + col];
        unsigned short h = f2bf(v);
        WThi[(size_t)m * 16384 + col * 128 + k] = h;
        WTlo[(size_t)m * 16384 + col * 128 + k] = f2bf(v - bf2f(h));
    } else if (i < 6 * 16384 + 3072) {
        int idx = i - 6 * 16384;
        int m = idx >> 9, rem = idx & 511, f = rem >> 2, c = rem & 3;
        int head = c & 1;
        const float* Wm = (m < 3) ? W1 + (size_t)m * 16384
                                  : W2 + (size_t)(m - 3) * 16384;
        const float* vec;
        if (m < 3) vec = ((c < 2) ? al1 : ar1) + m * 128 + head * 64;
        else       vec = ((c < 2) ? al2 : ar2) + (m - 3) * 128 + head * 64;
        float s = 0.f;
        for (int d = 0; d < 64; d++) s += Wm[f * 128 + head * 64 + d] * vec[d];
        P[m * 512 + f * 4 + c] = s;
    } else if (i < 6 * 16384 + 3072 + 256) {
        int idx = i - 6 * 16384 - 3072;
        int layer = idx >> 7, cc = idx & 127;
        const float* b = layer ? b2 : b1;
        bs[layer * 128 + cc] = b[cc] + b[128 + cc] + b[256 + cc];
    }
}

// ---------------------------------------------------------------------------
// Combined CSR over all 3 relations: key = r*N + dst.
// ---------------------------------------------------------------------------
__global__ __launch_bounds__(256) void hist3(
    const int* __restrict__ dst, int* __restrict__ deg, int E, int N)
{
    int e = blockIdx.x * 256 + threadIdx.x;
    if (e >= 3 * E) return;
    int r = (e >= 2 * E) ? 2 : (e >= E ? 1 : 0);
    atomicAdd(&deg[r * N + dst[e]], 1);
}

// inclusive scan, 1024 elems per 256-thread block (4/thread)
__global__ __launch_bounds__(256) void scan1(
    const int* __restrict__ deg, int* __restrict__ partial,
    int* __restrict__ bsum, int n)
{
    __shared__ int s[256];
    int t = threadIdx.x;
    int base = blockIdx.x * 1024 + t * 4;
    int v0 = (base     < n) ? deg[base]     : 0;
    int v1 = (base + 1 < n) ? deg[base + 1] : 0;
    int v2 = (base + 2 < n) ? deg[base + 2] : 0;
    int v3 = (base + 3 < n) ? deg[base + 3] : 0;
    int csum = v0 + v1 + v2 + v3;
    s[t] = csum;
    __syncthreads();
    for (int off = 1; off < 256; off <<= 1) {
        int x = (t >= off) ? s[t - off] : 0;
        __syncthreads();
        s[t] += x;
        __syncthreads();
    }
    int excl = s[t] - csum;
    int p0 = excl + v0, p1 = p0 + v1, p2 = p1 + v2, p3 = p2 + v3;
    if (base     < n) partial[base]     = p0;
    if (base + 1 < n) partial[base + 1] = p1;
    if (base + 2 < n) partial[base + 2] = p2;
    if (base + 3 < n) partial[base + 3] = p3;
    if (t == 255) bsum[blockIdx.x] = s[255];
}

// exclusive scan of block sums (nb <= 512)
__global__ __launch_bounds__(512) void scan2(int* __restrict__ bsum, int nb)
{
    __shared__ int s[512];
    int t = threadIdx.x;
    int v = (t < nb) ? bsum[t] : 0;
    s[t] = v;
    __syncthreads();
    for (int off = 1; off < 512; off <<= 1) {
        int x = (t >= off) ? s[t - off] : 0;
        __syncthreads();
        s[t] += x;
        __syncthreads();
    }
    if (t < nb) bsum[t] = s[t] - v;
}

__global__ __launch_bounds__(256) void scan3(
    const int* __restrict__ partial, const int* __restrict__ bsum,
    int* __restrict__ rowptr, int n)
{
    int i = blockIdx.x * 256 + threadIdx.x;
    if (i < n) rowptr[i + 1] = partial[i] + bsum[i >> 10];
    if (i == 0) rowptr[0] = 0;
}

__global__ __launch_bounds__(256) void place3(
    const int* __restrict__ src, const int* __restrict__ dst,
    const int* __restrict__ rowptr, int* __restrict__ cnt,
    int* __restrict__ csr_src, int E, int N)
{
    int e = blockIdx.x * 256 + threadIdx.x;
    if (e >= 3 * E) return;
    int r = (e >= 2 * E) ? 2 : (e >= E ? 1 : 0);
    int key = r * N + dst[e];
    int pos = rowptr[key] + atomicAdd(&cnt[key], 1);
    csr_src[pos] = src[e];
}

// ---------------------------------------------------------------------------
// elproj: per-layer pass over X. Produces (a) elr[n][12]: attention logit
// pieces for all 3 relations (c = r*4 + {el0,el1,er0,er1}); (b) Xb: bf16
// interleaved copy Xb[n][2d]=x[d], Xb[n][2d+1]=x[64+d] (gather source).
// ---------------------------------------------------------------------------
__global__ __launch_bounds__(256) void elproj(
    const float* __restrict__ Xin, const float* __restrict__ P,  // layer base (1536)
    float* __restrict__ elr, unsigned short* __restrict__ Xb,
    int n, int do_relu)
{
    __shared__ float Xs[16][128];
    __shared__ float Ps[1536];
    int t = threadIdx.x;
    int n0 = blockIdx.x * 16;

    for (int i = t; i < 1536; i += 256) Ps[i] = P[i];
    {
        int row = t >> 4, cb = (t & 15) * 8;
        int gn = n0 + row;
        float4 a = make_float4(0, 0, 0, 0), b = make_float4(0, 0, 0, 0);
        if (gn < n) {
            a = *(const float4*)(Xin + (size_t)gn * 128 + cb);
            b = *(const float4*)(Xin + (size_t)gn * 128 + cb + 4);
        }
        if (do_relu) {
            a.x = fmaxf(a.x, 0.f); a.y = fmaxf(a.y, 0.f);
            a.z = fmaxf(a.z, 0.f); a.w = fmaxf(a.w, 0.f);
            b.x = fmaxf(b.x, 0.f); b.y = fmaxf(b.y, 0.f);
            b.z = fmaxf(b.z, 0.f); b.w = fmaxf(b.w, 0.f);
        }
        *(float4*)&Xs[row][cb]     = a;
        *(float4*)&Xs[row][cb + 4] = b;
    }
    __syncthreads();

    if (t < 192) {
        int nl = t / 12, c = t % 12, r = c >> 2, j = c & 3;
        int gn = n0 + nl;
        if (gn < n) {
            float sum = 0.f;
            for (int k = 0; k < 128; k++)
                sum += Xs[nl][k] * Ps[r * 512 + k * 4 + j];
            elr[(size_t)gn * 12 + c] = sum;
        }
    }
    {
        int row = t >> 4, db = (t & 15) * 4;
        int gn = n0 + row;
        if (gn < n) {
#pragma unroll
            for (int i2 = 0; i2 < 4; i2++) {
                int d = db + i2;
                ushort2 v;
                v.x = f2bf(Xs[row][d]);
                v.y = f2bf(Xs[row][64 + d]);
                *(ushort2*)(Xb + (size_t)gn * 128 + 2 * d) = v;
            }
        }
    }
}

// ---------------------------------------------------------------------------
// aggregate (per relation): wave per node; lane-parallel softmax over
// in-edges, then PER-HEAD full-row weighted gather of bf16 X rows.
// Each edge's 128 features are read once (ushort2 per lane) and accumulated
// into BOTH heads' aggregates. Output Xag[node][256] bf16:
//   [0..127]  = sum_e alpha0_e * X[src_e][0..127]   (head-0 weights)
//   [128..255]= sum_e alpha1_e * X[src_e][0..127]   (head-1 weights)
// lane holds features (lane) and (64+lane) via interleaved Xb.
// ---------------------------------------------------------------------------
__global__ __launch_bounds__(256) void aggregate(
    const int* __restrict__ rowptr,         // already + r*N
    const int* __restrict__ csr_src,
    const float* __restrict__ elr,
    const unsigned short* __restrict__ Xb,
    unsigned short* __restrict__ Xag,
    int n, int roff)
{
    int node = (int)((blockIdx.x * 256 + threadIdx.x) >> 6);
    int lane = threadIdx.x & 63;
    if (node >= n) return;
    int beg = rowptr[node], end = rowptr[node + 1];
    int deg = end - beg;

    float a00 = 0.f, a01 = 0.f, a10 = 0.f, a11 = 0.f;
    if (deg > 0) {
        const float er0 = elr[(size_t)node * 12 + roff + 2];
        const float er1 = elr[(size_t)node * 12 + roff + 3];

        if (deg <= 64) {
            int s = 0;
            float v0 = -INFINITY, v1 = -INFINITY;
            if (lane < deg) {
                s = csr_src[beg + lane];
                float2 e = *(const float2*)(elr + (size_t)s * 12 + roff);
                v0 = leaky02(e.x + er0);
                v1 = leaky02(e.y + er1);
            }
            float M0 = v0, M1 = v1;
#pragma unroll
            for (int off = 32; off; off >>= 1) {
                M0 = fmaxf(M0, __shfl_xor(M0, off, 64));
                M1 = fmaxf(M1, __shfl_xor(M1, off, 64));
            }
            float x0 = (lane < deg) ? __expf(v0 - M0) : 0.0f;
            float x1 = (lane < deg) ? __expf(v1 - M1) : 0.0f;
            float S0 = x0, S1 = x1;
#pragma unroll
            for (int off = 32; off; off >>= 1) {
                S0 += __shfl_xor(S0, off, 64);
                S1 += __shfl_xor(S1, off, 64);
            }
            float w0 = x0 / S0;
            float w1 = x1 / S1;

            for (int j = 0; j < deg; j++) {
                int ss    = __shfl(s, j, 64);
                float ww0 = __shfl(w0, j, 64);
                float ww1 = __shfl(w1, j, 64);
                ushort2 xv = *(const ushort2*)(Xb + (size_t)ss * 128 + 2 * lane);
                float xa = bf2f(xv.x), xb = bf2f(xv.y);
                a00 += ww0 * xa; a01 += ww0 * xb;
                a10 += ww1 * xa; a11 += ww1 * xb;
            }
        } else {
            float m0 = -INFINITY, m1 = -INFINITY, d0 = 0.0f, d1 = 0.0f;
            for (int c0 = beg; c0 < end; c0 += 64) {
                int i = c0 + lane;
                float v0 = -INFINITY, v1 = -INFINITY;
                if (i < end) {
                    int s = csr_src[i];
                    float2 e = *(const float2*)(elr + (size_t)s * 12 + roff);
                    v0 = leaky02(e.x + er0);
                    v1 = leaky02(e.y + er1);
                }
                float M0 = v0, M1 = v1;
#pragma unroll
                for (int off = 32; off; off >>= 1) {
                    M0 = fmaxf(M0, __shfl_xor(M0, off, 64));
                    M1 = fmaxf(M1, __shfl_xor(M1, off, 64));
                }
                float x0 = (i < end) ? __expf(v0 - M0) : 0.0f;
                float x1 = (i < end) ? __expf(v1 - M1) : 0.0f;
                float S0 = x0, S1 = x1;
#pragma unroll
                for (int off = 32; off; off >>= 1) {
                    S0 += __shfl_xor(S0, off, 64);
                    S1 += __shfl_xor(S1, off, 64);
                }
                float nm0 = fmaxf(m0, M0), nm1 = fmaxf(m1, M1);
                d0 = d0 * __expf(m0 - nm0) + S0 * __expf(M0 - nm0);
                d1 = d1 * __expf(m1 - nm1) + S1 * __expf(M1 - nm1);
                m0 = nm0; m1 = nm1;
            }
            float inv0 = 1.0f / d0, inv1 = 1.0f / d1;
            for (int c0 = beg; c0 < end; c0 += 64) {
                int i = c0 + lane;
                int cn = min(64, end - c0);
                int s = 0; float w0 = 0.0f, w1 = 0.0f;
                if (i < end) {
                    s = csr_src[i];
                    float2 e = *(const float2*)(elr + (size_t)s * 12 + roff);
                    w0 = __expf(leaky02(e.x + er0) - m0) * inv0;
                    w1 = __expf(leaky02(e.y + er1) - m1) * inv1;
                }
                for (int j = 0; j < cn; j++) {
                    int ss    = __shfl(s, j, 64);
                    float ww0 = __shfl(w0, j, 64);
                    float ww1 = __shfl(w1, j, 64);
                    ushort2 xv = *(const ushort2*)(Xb + (size_t)ss * 128 + 2 * lane);
                    float xa = bf2f(xv.x), xb = bf2f(xv.y);
                    a00 += ww0 * xa; a01 += ww0 * xb;
                    a10 += ww1 * xa; a11 += ww1 * xb;
                }
            }
        }
    }
    unsigned short* xr = Xag + (size_t)node * 256;
    xr[lane]       = f2bf(a00);
    xr[64 + lane]  = f2bf(a01);
    xr[128 + lane] = f2bf(a10);
    xr[192 + lane] = f2bf(a11);
}

// ---------------------------------------------------------------------------
// MFMA GEMM: h (+)= Xagg(per-head) * W for one relation.
// A rows are 256 bf16: [head0 full 128 | head1 full 128]. Output cols 0..63
// (g=0..3) use the head-0 A-half; cols 64..127 (g=4..7) use head-1.
// W is hi/lo split bf16 (exact-ish); A is single bf16.
// mode 0: h = acc + bias ; mode 1: h += acc ;
// mode 2: out[n][d] = 0.5*((h[d]+acc_d) + (h[64+d]+acc_{64+d}))
// ---------------------------------------------------------------------------
__global__ __launch_bounds__(256) void gemm_acc(
    const unsigned short* __restrict__ Xag,
    const unsigned short* __restrict__ WThi, const unsigned short* __restrict__ WTlo,
    const float* __restrict__ bs,      // layer bias sums [128] (mode 0)
    float* __restrict__ h, float* __restrict__ out,
    int n, int mode)
{
    __shared__ short Ah[64 * 256];     // 32 KB, 512B rows, swizzled
    const int t    = threadIdx.x;
    const int row0 = blockIdx.x * 64;

    {
        int row = t >> 2, q = t & 3;
        int gn = row0 + row;
        const short8v* g8 = (const short8v*)(Xag + (size_t)gn * 256) + q * 8;
        char* aB = (char*)Ah + row * 512;
        int sw = (row & 7) << 4;
        bool valid = gn < n;
#pragma unroll
        for (int i = 0; i < 8; i++) {
            short8v v = {0,0,0,0,0,0,0,0};
            if (valid) v = g8[i];
            int off = (q * 128 + i * 16) ^ sw;
            *(short8v*)(aB + off) = v;
        }
    }
    __syncthreads();

    const int w  = t >> 6;
    const int l  = t & 63;
    const int lr = l & 15;
    const int lq = l >> 4;

    float4v acc[8];
#pragma unroll
    for (int g = 0; g < 8; g++) acc[g] = (float4v){0.f, 0.f, 0.f, 0.f};

    const int rowA = w * 16 + lr;
    const char* aB = (const char*)Ah + rowA * 512;
    const int swA = (rowA & 7) << 4;

#pragma unroll
    for (int ks = 0; ks < 4; ks++) {
        int base = ks * 64 + lq * 16;
        short8v x0 = *(const short8v*)(aB + (base ^ swA));          // head 0
        short8v x1 = *(const short8v*)(aB + ((256 + base) ^ swA));  // head 1
#pragma unroll
        for (int g = 0; g < 8; g++) {
            int bidx = (g * 16 + lr) * 128 + ks * 32 + lq * 8;
            short8v bh = *(const short8v*)(WThi + bidx);
            short8v bl = *(const short8v*)(WTlo + bidx);
            short8v xx = (g < 4) ? x0 : x1;
            acc[g] = __builtin_amdgcn_mfma_f32_16x16x32_bf16(xx, bh, acc[g], 0, 0, 0);
            acc[g] = __builtin_amdgcn_mfma_f32_16x16x32_bf16(xx, bl, acc[g], 0, 0, 0);
        }
    }

    if (mode == 0) {
        float bsv[8];
#pragma unroll
        for (int g = 0; g < 8; g++) bsv[g] = bs[g * 16 + lr];
#pragma unroll
        for (int rr = 0; rr < 4; rr++) {
            int gr = row0 + w * 16 + lq * 4 + rr;
            if (gr < n) {
                float* hr = h + (size_t)gr * 128;
#pragma unroll
                for (int g = 0; g < 8; g++) hr[g * 16 + lr] = acc[g][rr] + bsv[g];
            }
        }
    } else if (mode == 1) {
#pragma unroll
        for (int rr = 0; rr < 4; rr++) {
            int gr = row0 + w * 16 + lq * 4 + rr;
            if (gr < n) {
                float* hr = h + (size_t)gr * 128;
#pragma unroll
                for (int g = 0; g < 8; g++) hr[g * 16 + lr] += acc[g][rr];
            }
        }
    } else {
#pragma unroll
        for (int rr = 0; rr < 4; rr++) {
            int gr = row0 + w * 16 + lq * 4 + rr;
            if (gr < n) {
                const float* hr = h + (size_t)gr * 128;
#pragma unroll
                for (int g = 0; g < 4; g++) {
                    float t0 = hr[g * 16 + lr]      + acc[g][rr];
                    float t1 = hr[64 + g * 16 + lr] + acc[g + 4][rr];
                    out[(size_t)gr * 64 + g * 16 + lr] = 0.5f * (t0 + t1);
                }
            }
        }
    }
}

// ---------------------------------------------------------------------------
extern "C" void kernel_launch(void* const* d_in, const int* in_sizes, int n_in,
                              void* d_out, int out_size, void* d_ws, size_t ws_size,
                              hipStream_t stream)
{
    const float* x   = (const float*)d_in[0];
    const int*   src = (const int*)  d_in[1];
    const int*   dst = (const int*)  d_in[2];
    const float* W1  = (const float*)d_in[3];
    const float* al1 = (const float*)d_in[4];
    const float* ar1 = (const float*)d_in[5];
    const float* b1  = (const float*)d_in[6];
    const float* W2  = (const float*)d_in[7];
    const float* al2 = (const float*)d_in[8];
    const float* ar2 = (const float*)d_in[9];
    const float* b2  = (const float*)d_in[10];

    const int N = in_sizes[0] / NF;          // 100000
    const int E = in_sizes[1] / 3;           // 800000

    char* p = (char*)d_ws;
    float* h_buf = (float*)p;                  p += (size_t)N * 128 * 4;
    unsigned short* Xb = (unsigned short*)p;   p += (size_t)N * 128 * 2;
    unsigned short* Xag = (unsigned short*)p;  p += (size_t)N * 256 * 2;
    float* elr = (float*)p;                    p += (size_t)N * 12 * 4;
    unsigned short* WThi = (unsigned short*)p; p += 6 * 16384 * 2;
    unsigned short* WTlo = (unsigned short*)p; p += 6 * 16384 * 2;
    float* P  = (float*)p;                     p += 6 * 512 * 4;
    float* bs = (float*)p;                     p += 256 * 4;
    int* rowptr  = (int*)p;                    p += ((size_t)3 * N + 1) * 4;
    int* csr_src = (int*)p;                    p += (size_t)3 * E * 4;
    int* deg     = (int*)p;                    p += (size_t)3 * N * 4;
    int* cnt     = (int*)p;                    p += (size_t)3 * N * 4;   // adjacent to deg
    int* partial = (int*)p;                    p += (size_t)3 * N * 4;
    int* bsumS   = (int*)p;                    p += 512 * 4;

    const int n3 = 3 * N;
    const int scan1Blocks = (n3 + 1023) / 1024;

    prep<<<(6 * 16384 + 3072 + 256 + 255) / 256, 256, 0, stream>>>(
        W1, W2, al1, ar1, b1, al2, ar2, b2, WThi, WTlo, P, bs);

    hipMemsetAsync(deg, 0, (size_t)2 * n3 * 4, stream);   // deg + cnt
    hist3<<<(3 * E + 255) / 256, 256, 0, stream>>>(dst, deg, E, N);
    scan1<<<scan1Blocks, 256, 0, stream>>>(deg, partial, bsumS, n3);
    scan2<<<1, 512, 0, stream>>>(bsumS, scan1Blocks);
    scan3<<<(n3 + 255) / 256, 256, 0, stream>>>(partial, bsumS, rowptr, n3);
    place3<<<(3 * E + 255) / 256, 256, 0, stream>>>(src, dst, rowptr, cnt,
                                                    csr_src, E, N);

    const int aggBlocks  = (N + 3) / 4;
    const int gemmBlocks = (N + 63) / 64;
    const int projBlocks = (N + 15) / 16;

    // ---------------- layer 1 ----------------
    elproj<<<projBlocks, 256, 0, stream>>>(x, P, elr, Xb, N, 0);
    for (int r = 0; r < 3; r++) {
        aggregate<<<aggBlocks, 256, 0, stream>>>(
            rowptr + r * N, csr_src, elr, Xb, Xag, N, r * 4);
        gemm_acc<<<gemmBlocks, 256, 0, stream>>>(
            Xag, WThi + (size_t)r * 16384, WTlo + (size_t)r * 16384,
            bs, h_buf, nullptr, N, r == 0 ? 0 : 1);
    }

    // ---------------- layer 2 ----------------
    elproj<<<projBlocks, 256, 0, stream>>>(h_buf, P + 1536, elr, Xb, N, 1);
    for (int r = 0; r < 3; r++) {
        aggregate<<<aggBlocks, 256, 0, stream>>>(
            rowptr + r * N, csr_src, elr, Xb, Xag, N, r * 4);
        int mode = (r == 0) ? 0 : ((r == 2) ? 2 : 1);
        gemm_acc<<<gemmBlocks, 256, 0, stream>>>(
            Xag, WThi + (size_t)(3 + r) * 16384, WTlo + (size_t)(3 + r) * 16384,
            bs + 128, h_buf, (float*)d_out, N, mode);
    }
}